// Round 3
// baseline (2067.755 us; speedup 1.0000x reference)
//
#include <hip/hip_runtime.h>

#define B_ 8
#define C_ 128
#define L_ 4096
#define P_ 96
#define D_ 16

// Measurement round: internal repeat counts (idempotent re-execution) sized to
// push each kernel's dispatch above the ~160us harness fills -> per-kernel
// counters become visible in the rocprof top-5. Set all to 1 to restore the
// fastest known configuration (round-1 baseline, 526 us).
#define REP_CONV 4
#define REP_PROJ 10
#define REP_ATTN 14

typedef __attribute__((ext_vector_type(8))) short short8;
typedef __attribute__((ext_vector_type(16))) float float16v;

__device__ __forceinline__ unsigned short f2bf(float f) {
  unsigned int u = __float_as_uint(f);
  u += 0x7fff + ((u >> 16) & 1);          // round-to-nearest-even
  return (unsigned short)(u >> 16);
}

// ---------------------------------------------------------------------------
// Workspace layout (bytes)
// ---------------------------------------------------------------------------
constexpr size_t OFF_H      = 0;                      // h  [B][C][L] f32 : 16 MB
constexpr size_t OFF_PSUM   = 16777216;               // [C][2] f32
constexpr size_t OFF_PSUMSQ = OFF_PSUM + 8192;
constexpr size_t OFF_SCALE  = OFF_PSUMSQ + 8192;      // [C] f32
constexpr size_t OFF_SHIFT  = OFF_SCALE + 512;
constexpr size_t OFF_WALLT  = OFF_SHIFT + 512;        // WallT [c][r] f32 64 KB
constexpr size_t OFF_BALL   = OFF_WALLT + 65536;      // [128] f32
constexpr size_t OFF_QT     = OFF_BALL + 512;         // [B][L][16] bf16 (q pre-scaled by log2e)
constexpr size_t OFF_KT     = OFF_QT + 1048576;       // [B][L][16] bf16
constexpr size_t OFF_V2     = OFF_KT + 1048576;       // v2t [B][L/16][96][16] bf16 : 6 MB

// ---------------------------------------------------------------------------
// k_prep: rows 0..15 = Wq, 16..31 = Wk, 32..127 = Wv2 = W2 @ Wv.
// ---------------------------------------------------------------------------
__global__ __launch_bounds__(128) void k_prep(
    const float* __restrict__ Wq, const float* __restrict__ bq,
    const float* __restrict__ Wk, const float* __restrict__ bk,
    const float* __restrict__ Wv, const float* __restrict__ bv,
    const float* __restrict__ W2,
    float* __restrict__ wallT, float* __restrict__ ball)
{
  const int r = blockIdx.x;
  const int c = threadIdx.x;
  float wv;
  if (r < 16) {
    wv = Wq[r * C_ + c];
  } else if (r < 32) {
    wv = Wk[(r - 16) * C_ + c];
  } else {
    const int p = r - 32;
    float s = 0.f;
#pragma unroll 8
    for (int o = 0; o < C_; ++o) s += W2[p * C_ + o] * Wv[o * C_ + c];
    wv = s;
  }
  wallT[c * C_ + r] = wv;
  if (c == 0) {
    float bb;
    if (r < 16)      bb = bq[r];
    else if (r < 32) bb = bk[r - 16];
    else {
      const int p = r - 32;
      float s = 0.f;
#pragma unroll 8
      for (int o = 0; o < C_; ++o) s += W2[p * C_ + o] * bv[o];
      bb = s;
    }
    ball[r] = bb;
  }
}

// ---------------------------------------------------------------------------
// k_conv: h[b,o,l] = sum_i x[b,i] * Wt[i,o,l]. REP_CONV idempotent repeats.
// ---------------------------------------------------------------------------
__global__ __launch_bounds__(512) void k_conv(
    const float* __restrict__ x, const float* __restrict__ Wt,
    float* __restrict__ h, float* __restrict__ psum, float* __restrict__ psumsq)
{
  __shared__ float4 xs4[256];
  __shared__ float rs1[8], rs2[8];
  const int tid = threadIdx.x;
  const int o = blockIdx.y;
  const int l = blockIdx.x * 2048 + tid * 4;

  if (tid < 256) xs4[tid] = ((const float4*)x)[tid];
  __syncthreads();

#pragma unroll 1
  for (int rep = 0; rep < REP_CONV; ++rep) {
    float4 acc[8];
#pragma unroll
    for (int bb = 0; bb < 8; ++bb) acc[bb] = (float4){0.f, 0.f, 0.f, 0.f};

    const float* wp = Wt + (size_t)o * L_ + l;
    const size_t stride = (size_t)C_ * L_;
    const int phase = (blockIdx.y + blockIdx.x * 8) & 31;

    float4 wbuf[2][4];
#pragma unroll
    for (int q = 0; q < 4; ++q)
      wbuf[0][q] = *(const float4*)(wp + (size_t)(phase * 4 + q) * stride);

#pragma unroll 2
    for (int g = 0; g < 32; ++g) {
      const int cur = g & 1, nb = cur ^ 1;
      const int in4 = ((phase + g + 1) & 31) * 4;
#pragma unroll
      for (int q = 0; q < 4; ++q)
        wbuf[nb][q] = *(const float4*)(wp + (size_t)(in4 + q) * stride);

      const int ic = (phase + g) & 31;
#pragma unroll
      for (int bb = 0; bb < 8; ++bb) {
        const float4 xb = xs4[bb * 32 + ic];
        acc[bb].x += xb.x * wbuf[cur][0].x + xb.y * wbuf[cur][1].x + xb.z * wbuf[cur][2].x + xb.w * wbuf[cur][3].x;
        acc[bb].y += xb.x * wbuf[cur][0].y + xb.y * wbuf[cur][1].y + xb.z * wbuf[cur][2].y + xb.w * wbuf[cur][3].y;
        acc[bb].z += xb.x * wbuf[cur][0].z + xb.y * wbuf[cur][1].z + xb.z * wbuf[cur][2].z + xb.w * wbuf[cur][3].z;
        acc[bb].w += xb.x * wbuf[cur][0].w + xb.y * wbuf[cur][1].w + xb.z * wbuf[cur][2].w + xb.w * wbuf[cur][3].w;
      }
    }
    float s1 = 0.f, s2 = 0.f;
#pragma unroll
    for (int bb = 0; bb < 8; ++bb) {
      *(float4*)(h + ((size_t)(bb * C_ + o)) * L_ + l) = acc[bb];
      s1 += acc[bb].x + acc[bb].y + acc[bb].z + acc[bb].w;
      s2 += acc[bb].x * acc[bb].x + acc[bb].y * acc[bb].y
          + acc[bb].z * acc[bb].z + acc[bb].w * acc[bb].w;
    }
    for (int off = 1; off < 64; off <<= 1) {
      s1 += __shfl_xor(s1, off);
      s2 += __shfl_xor(s2, off);
    }
    if ((tid & 63) == 0) { rs1[tid >> 6] = s1; rs2[tid >> 6] = s2; }
    __syncthreads();
    if (tid == 0) {
      float a1 = 0.f, a2 = 0.f;
#pragma unroll
      for (int wv = 0; wv < 8; ++wv) { a1 += rs1[wv]; a2 += rs2[wv]; }
      psum[o * 2 + blockIdx.x]   = a1;
      psumsq[o * 2 + blockIdx.x] = a2;
    }
    __syncthreads();   // rs reuse in next rep
  }
}

// ---------------------------------------------------------------------------
// k_bn: finalize per-channel scale/shift.
// ---------------------------------------------------------------------------
__global__ __launch_bounds__(128) void k_bn(
    const float* __restrict__ psum, const float* __restrict__ psumsq,
    const float* __restrict__ gamma, const float* __restrict__ beta,
    float* __restrict__ scale, float* __restrict__ shift)
{
  const int c = threadIdx.x;
  float s1 = 0.f, s2 = 0.f;
  for (int t = 0; t < 2; ++t) { s1 += psum[c * 2 + t]; s2 += psumsq[c * 2 + t]; }
  const float inv = 1.f / 32768.f;
  const float mean = s1 * inv;
  const float var  = s2 * inv - mean * mean;
  const float sc   = rsqrtf(var + 1e-5f) * gamma[c];
  scale[c] = sc;
  shift[c] = beta[c] - mean * sc;
}

// ---------------------------------------------------------------------------
// k_proj: [q;k;v2] = Wall @ relu(bn(h)) + ball, bf16 out. REP_PROJ repeats.
// ---------------------------------------------------------------------------
__global__ __launch_bounds__(256) void k_proj(
    const float* __restrict__ h, const float* __restrict__ scale,
    const float* __restrict__ shift, const float* __restrict__ wallT,
    const float* __restrict__ ball,
    unsigned short* __restrict__ qT, unsigned short* __restrict__ kT,
    unsigned short* __restrict__ v2t)
{
  __shared__ __align__(16) char sm[128 * 68 * 4];     // 34 KB
  float* hn = (float*)sm;                             // [c][68] f32, 64 used
  unsigned short* v2s = (unsigned short*)sm;          // reused: [p][72] bf16

  const int b = blockIdx.y;
  const int l0 = blockIdx.x * 64;
  const int tid = threadIdx.x;

#pragma unroll 1
  for (int rep = 0; rep < REP_PROJ; ++rep) {
    // stage + bn + relu: 128c x 64l tile
#pragma unroll
    for (int i = 0; i < 8; ++i) {
      const int idx = tid + i * 256;
      const int c = idx >> 4, lq = (idx & 15) * 4;
      const float4 hv = *(const float4*)(h + ((size_t)(b * C_ + c)) * L_ + l0 + lq);
      const float sc = scale[c], sh = shift[c];
      float4 r;
      r.x = fmaxf(hv.x * sc + sh, 0.f);
      r.y = fmaxf(hv.y * sc + sh, 0.f);
      r.z = fmaxf(hv.z * sc + sh, 0.f);
      r.w = fmaxf(hv.w * sc + sh, 0.f);
      *(float4*)(hn + c * 68 + lq) = r;
    }
    __syncthreads();

    const int wu = __builtin_amdgcn_readfirstlane(tid) >> 6;  // wave id, uniform
    const int lane = tid & 63;
    const int l = l0 + lane;

    float acc[32];
#pragma unroll
    for (int r = 0; r < 32; ++r) acc[r] = ball[wu * 32 + r];

#pragma unroll 4
    for (int c = 0; c < C_; ++c) {
      const float hv = hn[c * 68 + lane];
      const float* wrow = wallT + c * C_ + wu * 32;   // wave-uniform: s_load
#pragma unroll
      for (int r = 0; r < 32; ++r) acc[r] += wrow[r] * hv;
    }
    __syncthreads();   // all waves done reading hn before LDS reuse

    if (wu == 0) {
      const size_t row = (size_t)(b * L_ + l) * D_;
      short8 v0, v1;
#pragma unroll
      for (int r = 0; r < 8; ++r) {
        v0[r] = (short)f2bf(acc[r] * 1.44269504f);        // q * log2(e)
        v1[r] = (short)f2bf(acc[8 + r] * 1.44269504f);
      }
      *(short8*)(qT + row) = v0;  *(short8*)(qT + row + 8) = v1;
#pragma unroll
      for (int r = 0; r < 8; ++r) { v0[r] = (short)f2bf(acc[16 + r]); v1[r] = (short)f2bf(acc[24 + r]); }
      *(short8*)(kT + row) = v0;  *(short8*)(kT + row + 8) = v1;
    } else {
      const int pbase = wu * 32 - 32;
#pragma unroll
      for (int r = 0; r < 32; ++r)
        v2s[(pbase + r) * 72 + lane] = f2bf(acc[r]);
    }
    __syncthreads();

    // v2 stores, m-tiled: fully coalesced consecutive 8B stores
#pragma unroll
    for (int i = 0; i < 6; ++i) {
      const int j = tid + i * 256;
      const int mo4 = j & 3;
      const int jp = j >> 2;
      const int p = jp % 96;
      const int mtl = jp / 96;                       // 0..3
      const uint2 val = *(const uint2*)(v2s + p * 72 + mtl * 16 + mo4 * 4);
      *(uint2*)(v2t + ((size_t)((b * (L_ / 16) + blockIdx.x * 4 + mtl)) * P_ + p) * 16
                + mo4 * 4) = val;
    }
    __syncthreads();   // LDS (v2s/hn alias) reuse in next rep
  }
}

// ---------------------------------------------------------------------------
// k_attn: transposed flash attention, 32x32x16 bf16 MFMA. REP_ATTN repeats.
// ---------------------------------------------------------------------------
__global__ __launch_bounds__(1024, 4) void k_attn(
    const unsigned short* __restrict__ qT, const unsigned short* __restrict__ kT,
    const unsigned short* __restrict__ v2t, const float* __restrict__ b2,
    float* __restrict__ y)
{
  __shared__ float ldsO[P_ * 128];   // [p][l] 48 KB
  __shared__ float ldsL[128];

  const int b = blockIdx.y;
  const int l0 = blockIdx.x * 128;
  const int tid = threadIdx.x;
  const int w  = tid >> 6;
  const int qg = w & 3;          // q-group
  const int ms = w >> 2;         // m-slice
  const int lane = tid & 63;
  const int col = lane & 31;
  const int hh  = lane >> 5;     // half-wave

#pragma unroll 1
  for (int rep = 0; rep < REP_ATTN; ++rep) {
#pragma unroll
    for (int i = 0; i < 12; ++i) ldsO[tid + i * 1024] = 0.f;
    if (tid < 128) ldsL[tid] = 0.f;
    __syncthreads();

    const int lq = l0 + qg * 32 + col;
    const short8 qf = *(const short8*)(qT + ((size_t)(b * L_ + lq)) * D_ + hh * 8);

    float16v oacc[3];
#pragma unroll
    for (int pt = 0; pt < 3; ++pt)
#pragma unroll
      for (int r = 0; r < 16; ++r) oacc[pt][r] = 0.f;
    float lsum = 0.f;

    const unsigned short* kbase =
        kT + ((size_t)(b * L_ + ms * 1024 + col)) * D_ + hh * 8;
    const unsigned short* vtb = v2t + (size_t)b * (L_ / 16) * P_ * 16
                                + (size_t)col * 16 + hh * 8;

    short8 kf_cur = *(const short8*)(kbase);

#pragma unroll 2
    for (int it = 0; it < 32; ++it) {
      const int itn = (it + 1) & 31;                 // wrap: always valid
      const short8 kf_nxt = *(const short8*)(kbase + (size_t)itn * 32 * D_);

      float16v zero;
#pragma unroll
      for (int r = 0; r < 16; ++r) zero[r] = 0.f;
      const float16v s = __builtin_amdgcn_mfma_f32_32x32x16_bf16(kf_cur, qf, zero, 0, 0, 0);

      const int mt16 = ms * 64 + it * 2;             // m-tile index

#pragma unroll
      for (int mt = 0; mt < 2; ++mt) {
        short8 vf[3];
#pragma unroll
        for (int pt = 0; pt < 3; ++pt)
          vf[pt] = *(const short8*)(vtb + ((size_t)(mt16 + mt) * P_ + pt * 32) * 16);

        unsigned dw[4];
#pragma unroll
        for (int g = 0; g < 4; ++g) {
          const float e0 = __builtin_amdgcn_exp2f(s[8 * mt + 2 * g]);
          const float e1 = __builtin_amdgcn_exp2f(s[8 * mt + 2 * g + 1]);
          lsum += e0 + e1;
          const unsigned u0 = __float_as_uint(e0) + 0x8000u;
          const unsigned u1 = __float_as_uint(e1) + 0x8000u;
          dw[g] = __builtin_amdgcn_perm(u1, u0, 0x07060302u);  // (bf(e1)<<16)|bf(e0)
        }

        const unsigned t0 = hh ? dw[0] : dw[2];
        const unsigned t1 = hh ? dw[1] : dw[3];
        const unsigned r0 = (unsigned)__shfl_xor((int)t0, 32);
        const unsigned r1 = (unsigned)__shfl_xor((int)t1, 32);
        union { int4 i; short8 s8; } pu;
        pu.i.x = hh ? (int)r0 : (int)dw[0];
        pu.i.y = hh ? (int)r1 : (int)dw[1];
        pu.i.z = hh ? (int)dw[2] : (int)r0;
        pu.i.w = hh ? (int)dw[3] : (int)r1;
        const short8 pf = pu.s8;
#pragma unroll
        for (int pt = 0; pt < 3; ++pt)
          oacc[pt] = __builtin_amdgcn_mfma_f32_32x32x16_bf16(vf[pt], pf, oacc[pt], 0, 0, 0);
      }
      kf_cur = kf_nxt;
    }

    atomicAdd(&ldsL[qg * 32 + col], lsum);
#pragma unroll
    for (int pt = 0; pt < 3; ++pt)
#pragma unroll
      for (int r = 0; r < 16; ++r) {
        const int p = (r & 3) + 8 * (r >> 2) + 4 * hh + 32 * pt;
        atomicAdd(&ldsO[p * 128 + qg * 32 + col], oacc[pt][r]);
      }
    __syncthreads();

#pragma unroll
    for (int i = 0; i < 12; ++i) {
      const int idx = tid + i * 1024;
      const int p = idx >> 7;
      const int l = idx & 127;
      y[((size_t)(b * P_ + p)) * L_ + l0 + l] = ldsO[idx] / ldsL[l] + b2[p];
    }
    __syncthreads();   // y done before next rep re-zeroes ldsO
  }
}

// ---------------------------------------------------------------------------
extern "C" void kernel_launch(void* const* d_in, const int* in_sizes, int n_in,
                              void* d_out, int out_size, void* d_ws, size_t ws_size,
                              hipStream_t stream) {
  (void)in_sizes; (void)n_in; (void)out_size; (void)ws_size;
  const float* x     = (const float*)d_in[0];
  const float* Wt    = (const float*)d_in[1];
  // d_in[2] = bt: unused — BatchNorm mean-subtraction cancels it exactly.
  const float* gamma = (const float*)d_in[3];
  const float* beta  = (const float*)d_in[4];
  const float* Wq    = (const float*)d_in[5];
  const float* bq    = (const float*)d_in[6];
  const float* Wk    = (const float*)d_in[7];
  const float* bk    = (const float*)d_in[8];
  const float* Wv    = (const float*)d_in[9];
  const float* bv    = (const float*)d_in[10];
  const float* W2    = (const float*)d_in[11];
  const float* b2    = (const float*)d_in[12];
  float* y = (float*)d_out;

  char* ws = (char*)d_ws;
  float* h       = (float*)(ws + OFF_H);
  float* psum    = (float*)(ws + OFF_PSUM);
  float* psumsq  = (float*)(ws + OFF_PSUMSQ);
  float* scale   = (float*)(ws + OFF_SCALE);
  float* shift   = (float*)(ws + OFF_SHIFT);
  float* wallT   = (float*)(ws + OFF_WALLT);
  float* ball    = (float*)(ws + OFF_BALL);
  unsigned short* qT  = (unsigned short*)(ws + OFF_QT);
  unsigned short* kT  = (unsigned short*)(ws + OFF_KT);
  unsigned short* v2t = (unsigned short*)(ws + OFF_V2);

  k_prep<<<128, 128, 0, stream>>>(Wq, bq, Wk, bk, Wv, bv, W2, wallT, ball);
  k_conv<<<dim3(2, 128), 512, 0, stream>>>(x, Wt, h, psum, psumsq);
  k_bn<<<1, 128, 0, stream>>>(psum, psumsq, gamma, beta, scale, shift);
  k_proj<<<dim3(64, 8), 256, 0, stream>>>(h, scale, shift, wallT, ball, qT, kT, v2t);
  k_attn<<<dim3(32, 8), 1024, 0, stream>>>(qT, kT, v2t, b2, y);
}

// Round 4
// 1053.764 us; speedup vs baseline: 1.9623x; 1.9623x over previous
//
#include <hip/hip_runtime.h>

#define B_ 8
#define C_ 128
#define L_ 4096
#define P_ 96
#define D_ 16

typedef __attribute__((ext_vector_type(8))) short short8;
typedef __attribute__((ext_vector_type(16))) float float16v;

__device__ __forceinline__ unsigned short f2bf(float f) {
  unsigned int u = __float_as_uint(f);
  u += 0x7fff + ((u >> 16) & 1);          // round-to-nearest-even
  return (unsigned short)(u >> 16);
}

// ---------------------------------------------------------------------------
// Workspace layout (bytes)
// ---------------------------------------------------------------------------
constexpr size_t OFF_H      = 0;                      // h  [B][C][L] f32 : 16 MB
constexpr size_t OFF_PSUM   = 16777216;               // [C][2] f32
constexpr size_t OFF_PSUMSQ = OFF_PSUM + 8192;
constexpr size_t OFF_SCALE  = OFF_PSUMSQ + 8192;      // [C] f32
constexpr size_t OFF_SHIFT  = OFF_SCALE + 512;
constexpr size_t OFF_WALLT  = OFF_SHIFT + 512;        // WallT [c][r] f32 64 KB
constexpr size_t OFF_BALL   = OFF_WALLT + 65536;      // [128] f32
constexpr size_t OFF_QT     = OFF_BALL + 512;         // [B][L][16] bf16 (q pre-scaled by log2e)
constexpr size_t OFF_KT     = OFF_QT + 1048576;       // [B][L][16] bf16
constexpr size_t OFF_V2     = OFF_KT + 1048576;       // v2t [B][L/16][96][16] bf16 : 6 MB

// ---------------------------------------------------------------------------
// k_prep: rows 0..15 = Wq, 16..31 = Wk, 32..127 = Wv2 = W2 @ Wv.
// ---------------------------------------------------------------------------
__global__ __launch_bounds__(128) void k_prep(
    const float* __restrict__ Wq, const float* __restrict__ bq,
    const float* __restrict__ Wk, const float* __restrict__ bk,
    const float* __restrict__ Wv, const float* __restrict__ bv,
    const float* __restrict__ W2,
    float* __restrict__ wallT, float* __restrict__ ball)
{
  const int r = blockIdx.x;
  const int c = threadIdx.x;
  float wv;
  if (r < 16) {
    wv = Wq[r * C_ + c];
  } else if (r < 32) {
    wv = Wk[(r - 16) * C_ + c];
  } else {
    const int p = r - 32;
    float s = 0.f;
#pragma unroll 8
    for (int o = 0; o < C_; ++o) s += W2[p * C_ + o] * Wv[o * C_ + c];
    wv = s;
  }
  wallT[c * C_ + r] = wv;
  if (c == 0) {
    float bb;
    if (r < 16)      bb = bq[r];
    else if (r < 32) bb = bk[r - 16];
    else {
      const int p = r - 32;
      float s = 0.f;
#pragma unroll 8
      for (int o = 0; o < C_; ++o) s += W2[p * C_ + o] * bv[o];
      bb = s;
    }
    ball[r] = bb;
  }
}

// ---------------------------------------------------------------------------
// k_conv: h[b,o,l] = sum_i x[b,i] * Wt[i,o,l]. Measured ~40 us/pass = at the
// 256 MB Wt read-once roofline. Unchanged.
// ---------------------------------------------------------------------------
__global__ __launch_bounds__(512) void k_conv(
    const float* __restrict__ x, const float* __restrict__ Wt,
    float* __restrict__ h, float* __restrict__ psum, float* __restrict__ psumsq)
{
  __shared__ float4 xs4[256];
  __shared__ float rs1[8], rs2[8];
  const int tid = threadIdx.x;
  const int o = blockIdx.y;
  const int l = blockIdx.x * 2048 + tid * 4;

  if (tid < 256) xs4[tid] = ((const float4*)x)[tid];
  __syncthreads();

  float4 acc[8];
#pragma unroll
  for (int bb = 0; bb < 8; ++bb) acc[bb] = (float4){0.f, 0.f, 0.f, 0.f};

  const float* wp = Wt + (size_t)o * L_ + l;
  const size_t stride = (size_t)C_ * L_;
  const int phase = (blockIdx.y + blockIdx.x * 8) & 31;

  float4 wbuf[2][4];
#pragma unroll
  for (int q = 0; q < 4; ++q)
    wbuf[0][q] = *(const float4*)(wp + (size_t)(phase * 4 + q) * stride);

#pragma unroll 2
  for (int g = 0; g < 32; ++g) {
    const int cur = g & 1, nb = cur ^ 1;
    const int in4 = ((phase + g + 1) & 31) * 4;
#pragma unroll
    for (int q = 0; q < 4; ++q)
      wbuf[nb][q] = *(const float4*)(wp + (size_t)(in4 + q) * stride);

    const int ic = (phase + g) & 31;
#pragma unroll
    for (int bb = 0; bb < 8; ++bb) {
      const float4 xb = xs4[bb * 32 + ic];
      acc[bb].x += xb.x * wbuf[cur][0].x + xb.y * wbuf[cur][1].x + xb.z * wbuf[cur][2].x + xb.w * wbuf[cur][3].x;
      acc[bb].y += xb.x * wbuf[cur][0].y + xb.y * wbuf[cur][1].y + xb.z * wbuf[cur][2].y + xb.w * wbuf[cur][3].y;
      acc[bb].z += xb.x * wbuf[cur][0].z + xb.y * wbuf[cur][1].z + xb.z * wbuf[cur][2].z + xb.w * wbuf[cur][3].z;
      acc[bb].w += xb.x * wbuf[cur][0].w + xb.y * wbuf[cur][1].w + xb.z * wbuf[cur][2].w + xb.w * wbuf[cur][3].w;
    }
  }
  float s1 = 0.f, s2 = 0.f;
#pragma unroll
  for (int bb = 0; bb < 8; ++bb) {
    *(float4*)(h + ((size_t)(bb * C_ + o)) * L_ + l) = acc[bb];
    s1 += acc[bb].x + acc[bb].y + acc[bb].z + acc[bb].w;
    s2 += acc[bb].x * acc[bb].x + acc[bb].y * acc[bb].y
        + acc[bb].z * acc[bb].z + acc[bb].w * acc[bb].w;
  }
  for (int off = 1; off < 64; off <<= 1) {
    s1 += __shfl_xor(s1, off);
    s2 += __shfl_xor(s2, off);
  }
  if ((tid & 63) == 0) { rs1[tid >> 6] = s1; rs2[tid >> 6] = s2; }
  __syncthreads();
  if (tid == 0) {
    float a1 = 0.f, a2 = 0.f;
#pragma unroll
    for (int wv = 0; wv < 8; ++wv) { a1 += rs1[wv]; a2 += rs2[wv]; }
    psum[o * 2 + blockIdx.x]   = a1;
    psumsq[o * 2 + blockIdx.x] = a2;
  }
}

// ---------------------------------------------------------------------------
// k_bn: finalize per-channel scale/shift.
// ---------------------------------------------------------------------------
__global__ __launch_bounds__(128) void k_bn(
    const float* __restrict__ psum, const float* __restrict__ psumsq,
    const float* __restrict__ gamma, const float* __restrict__ beta,
    float* __restrict__ scale, float* __restrict__ shift)
{
  const int c = threadIdx.x;
  float s1 = 0.f, s2 = 0.f;
  for (int t = 0; t < 2; ++t) { s1 += psum[c * 2 + t]; s2 += psumsq[c * 2 + t]; }
  const float inv = 1.f / 32768.f;
  const float mean = s1 * inv;
  const float var  = s2 * inv - mean * mean;
  const float sc   = rsqrtf(var + 1e-5f) * gamma[c];
  scale[c] = sc;
  shift[c] = beta[c] - mean * sc;
}

// ---------------------------------------------------------------------------
// k_proj: [q;k;v2] = Wall @ relu(bn(h)) + ball, bf16 out. Measured ~16 us.
// Unchanged.
// ---------------------------------------------------------------------------
__global__ __launch_bounds__(256) void k_proj(
    const float* __restrict__ h, const float* __restrict__ scale,
    const float* __restrict__ shift, const float* __restrict__ wallT,
    const float* __restrict__ ball,
    unsigned short* __restrict__ qT, unsigned short* __restrict__ kT,
    unsigned short* __restrict__ v2t)
{
  __shared__ __align__(16) char sm[128 * 68 * 4];     // 34 KB
  float* hn = (float*)sm;                             // [c][68] f32, 64 used
  unsigned short* v2s = (unsigned short*)sm;          // reused: [p][72] bf16

  const int b = blockIdx.y;
  const int l0 = blockIdx.x * 64;
  const int tid = threadIdx.x;

#pragma unroll
  for (int i = 0; i < 8; ++i) {
    const int idx = tid + i * 256;
    const int c = idx >> 4, lq = (idx & 15) * 4;
    const float4 hv = *(const float4*)(h + ((size_t)(b * C_ + c)) * L_ + l0 + lq);
    const float sc = scale[c], sh = shift[c];
    float4 r;
    r.x = fmaxf(hv.x * sc + sh, 0.f);
    r.y = fmaxf(hv.y * sc + sh, 0.f);
    r.z = fmaxf(hv.z * sc + sh, 0.f);
    r.w = fmaxf(hv.w * sc + sh, 0.f);
    *(float4*)(hn + c * 68 + lq) = r;
  }
  __syncthreads();

  const int wu = __builtin_amdgcn_readfirstlane(tid) >> 6;  // wave id, uniform
  const int lane = tid & 63;
  const int l = l0 + lane;

  float acc[32];
#pragma unroll
  for (int r = 0; r < 32; ++r) acc[r] = ball[wu * 32 + r];

#pragma unroll 4
  for (int c = 0; c < C_; ++c) {
    const float hv = hn[c * 68 + lane];
    const float* wrow = wallT + c * C_ + wu * 32;   // wave-uniform: s_load
#pragma unroll
    for (int r = 0; r < 32; ++r) acc[r] += wrow[r] * hv;
  }
  __syncthreads();   // all waves done reading hn before LDS reuse

  if (wu == 0) {
    const size_t row = (size_t)(b * L_ + l) * D_;
    short8 v0, v1;
#pragma unroll
    for (int r = 0; r < 8; ++r) {
      v0[r] = (short)f2bf(acc[r] * 1.44269504f);        // q * log2(e)
      v1[r] = (short)f2bf(acc[8 + r] * 1.44269504f);
    }
    *(short8*)(qT + row) = v0;  *(short8*)(qT + row + 8) = v1;
#pragma unroll
    for (int r = 0; r < 8; ++r) { v0[r] = (short)f2bf(acc[16 + r]); v1[r] = (short)f2bf(acc[24 + r]); }
    *(short8*)(kT + row) = v0;  *(short8*)(kT + row + 8) = v1;
  } else {
    const int pbase = wu * 32 - 32;
#pragma unroll
    for (int r = 0; r < 32; ++r)
      v2s[(pbase + r) * 72 + lane] = f2bf(acc[r]);
  }
  __syncthreads();

  // v2 stores, m-tiled: fully coalesced consecutive 8B stores
#pragma unroll
  for (int i = 0; i < 6; ++i) {
    const int j = tid + i * 256;
    const int mo4 = j & 3;
    const int jp = j >> 2;
    const int p = jp % 96;
    const int mtl = jp / 96;                       // 0..3
    const uint2 val = *(const uint2*)(v2s + p * 72 + mtl * 16 + mo4 * 4);
    *(uint2*)(v2t + ((size_t)((b * (L_ / 16) + blockIdx.x * 4 + mtl)) * P_ + p) * 16
              + mo4 * 4) = val;
  }
}

// ---------------------------------------------------------------------------
// k_attn v3: occupancy fix. Round-2 measurement: 106 us/pass, MfmaUtil 12%,
// VALUBusy 22%, HBM 6%, Occupancy 48% (grid 256 blocks = 1 block/CU = 4
// waves/SIMD) -> latency-bound, per-iter serial chain exposed (~8000 cyc/it).
// Now: 512-thr blocks (8 waves), q-tile 32 rows, m-range split 8 ways
// (16 iters x 32 m per wave). Grid (128,8) = 1024 blocks = 4 blocks/CU =
// 32 waves/CU. LDS 12.2 KB/block (4 fit). launch_bounds(512,8) pins VGPR<=64
// so 8 waves/SIMD are actually resident. Math/layouts unchanged.
// ---------------------------------------------------------------------------
__global__ __launch_bounds__(512, 8) void k_attn(
    const unsigned short* __restrict__ qT, const unsigned short* __restrict__ kT,
    const unsigned short* __restrict__ v2t, const float* __restrict__ b2,
    float* __restrict__ y)
{
  __shared__ float ldsO[P_ * 32];   // [p][l] 12 KB
  __shared__ float ldsL[32];

  const int b  = blockIdx.y;
  const int l0 = blockIdx.x * 32;
  const int tid = threadIdx.x;
  const int ms = tid >> 6;       // m-slice 0..7 (512 m each)
  const int lane = tid & 63;
  const int col = lane & 31;
  const int hh  = lane >> 5;     // half-wave

#pragma unroll
  for (int i = 0; i < 6; ++i) ldsO[tid + i * 512] = 0.f;
  if (tid < 32) ldsL[tid] = 0.f;
  __syncthreads();

  // Q^T B-fragment: B[k=8*hh+j][n=col], row lq of qT
  const int lq = l0 + col;
  const short8 qf = *(const short8*)(qT + ((size_t)(b * L_ + lq)) * D_ + hh * 8);

  float16v oacc[3];
#pragma unroll
  for (int pt = 0; pt < 3; ++pt)
#pragma unroll
    for (int r = 0; r < 16; ++r) oacc[pt][r] = 0.f;
  float lsum = 0.f;

  const unsigned short* kbase =
      kT + ((size_t)(b * L_ + ms * 512 + col)) * D_ + hh * 8;
  // v2t base for this batch; fragment (mt16, pt) at ((mt16)*96 + pt*32+col)*16 + hh*8
  const unsigned short* vtb = v2t + (size_t)b * (L_ / 16) * P_ * 16
                              + (size_t)col * 16 + hh * 8;

  short8 kf_cur = *(const short8*)(kbase);

#pragma unroll 2
  for (int it = 0; it < 16; ++it) {
    // prefetch next K-frag (head of the S dependency chain)
    const int itn = (it + 1) & 15;                 // wrap: always valid
    const short8 kf_nxt = *(const short8*)(kbase + (size_t)itn * 32 * D_);

    float16v zero;
#pragma unroll
    for (int r = 0; r < 16; ++r) zero[r] = 0.f;
    const float16v s = __builtin_amdgcn_mfma_f32_32x32x16_bf16(kf_cur, qf, zero, 0, 0, 0);

    const int mt16 = ms * 32 + it * 2;             // m-tile index (16 m per tile)

#pragma unroll
    for (int mt = 0; mt < 2; ++mt) {
      // issue this 16-m chunk's V-frags first; the exp chain hides their latency
      short8 vf[3];
#pragma unroll
      for (int pt = 0; pt < 3; ++pt)
        vf[pt] = *(const short8*)(vtb + ((size_t)(mt16 + mt) * P_ + pt * 32) * 16);

      // P = exp2(S^T) for this chunk; pack bf16 pairs
      unsigned dw[4];
#pragma unroll
      for (int g = 0; g < 4; ++g) {
        const float e0 = __builtin_amdgcn_exp2f(s[8 * mt + 2 * g]);
        const float e1 = __builtin_amdgcn_exp2f(s[8 * mt + 2 * g + 1]);
        lsum += e0 + e1;
        const unsigned u0 = __float_as_uint(e0) + 0x8000u;
        const unsigned u1 = __float_as_uint(e1) + 0x8000u;
        dw[g] = __builtin_amdgcn_perm(u1, u0, 0x07060302u);  // (bf(e1)<<16)|bf(e0)
      }

      // build P^T B-frag for k = mt*16 + 8*hh + j via half-wave exchange
      const unsigned t0 = hh ? dw[0] : dw[2];
      const unsigned t1 = hh ? dw[1] : dw[3];
      const unsigned r0 = (unsigned)__shfl_xor((int)t0, 32);
      const unsigned r1 = (unsigned)__shfl_xor((int)t1, 32);
      union { int4 i; short8 s8; } pu;
      pu.i.x = hh ? (int)r0 : (int)dw[0];
      pu.i.y = hh ? (int)r1 : (int)dw[1];
      pu.i.z = hh ? (int)dw[2] : (int)r0;
      pu.i.w = hh ? (int)dw[3] : (int)r1;
      const short8 pf = pu.s8;
#pragma unroll
      for (int pt = 0; pt < 3; ++pt)
        oacc[pt] = __builtin_amdgcn_mfma_f32_32x32x16_bf16(vf[pt], pf, oacc[pt], 0, 0, 0);
    }
    kf_cur = kf_nxt;
  }

  // combine partials across m-slices (and half-waves) in LDS
  atomicAdd(&ldsL[col], lsum);
#pragma unroll
  for (int pt = 0; pt < 3; ++pt)
#pragma unroll
    for (int r = 0; r < 16; ++r) {
      const int p = (r & 3) + 8 * (r >> 2) + 4 * hh + 32 * pt;
      atomicAdd(&ldsO[p * 32 + col], oacc[pt][r]);
    }
  __syncthreads();

  // y[b,p,l0+l] = O^T[p][l]/lsum[l] + b2[p]
#pragma unroll
  for (int i = 0; i < 6; ++i) {
    const int idx = tid + i * 512;
    const int p = idx >> 5;
    const int l = idx & 31;
    y[((size_t)(b * P_ + p)) * L_ + l0 + l] = ldsO[idx] / ldsL[l] + b2[p];
  }
}

// ---------------------------------------------------------------------------
extern "C" void kernel_launch(void* const* d_in, const int* in_sizes, int n_in,
                              void* d_out, int out_size, void* d_ws, size_t ws_size,
                              hipStream_t stream) {
  (void)in_sizes; (void)n_in; (void)out_size; (void)ws_size;
  const float* x     = (const float*)d_in[0];
  const float* Wt    = (const float*)d_in[1];
  // d_in[2] = bt: unused — BatchNorm mean-subtraction cancels it exactly.
  const float* gamma = (const float*)d_in[3];
  const float* beta  = (const float*)d_in[4];
  const float* Wq    = (const float*)d_in[5];
  const float* bq    = (const float*)d_in[6];
  const float* Wk    = (const float*)d_in[7];
  const float* bk    = (const float*)d_in[8];
  const float* Wv    = (const float*)d_in[9];
  const float* bv    = (const float*)d_in[10];
  const float* W2    = (const float*)d_in[11];
  const float* b2    = (const float*)d_in[12];
  float* y = (float*)d_out;

  char* ws = (char*)d_ws;
  float* h       = (float*)(ws + OFF_H);
  float* psum    = (float*)(ws + OFF_PSUM);
  float* psumsq  = (float*)(ws + OFF_PSUMSQ);
  float* scale   = (float*)(ws + OFF_SCALE);
  float* shift   = (float*)(ws + OFF_SHIFT);
  float* wallT   = (float*)(ws + OFF_WALLT);
  float* ball    = (float*)(ws + OFF_BALL);
  unsigned short* qT  = (unsigned short*)(ws + OFF_QT);
  unsigned short* kT  = (unsigned short*)(ws + OFF_KT);
  unsigned short* v2t = (unsigned short*)(ws + OFF_V2);

  k_prep<<<128, 128, 0, stream>>>(Wq, bq, Wk, bk, Wv, bv, W2, wallT, ball);
  k_conv<<<dim3(2, 128), 512, 0, stream>>>(x, Wt, h, psum, psumsq);
  k_bn<<<1, 128, 0, stream>>>(psum, psumsq, gamma, beta, scale, shift);
  k_proj<<<dim3(64, 8), 256, 0, stream>>>(h, scale, shift, wallT, ball, qT, kT, v2t);
  k_attn<<<dim3(128, 8), 512, 0, stream>>>(qT, kT, v2t, b2, y);
}

// Round 5
// 524.198 us; speedup vs baseline: 3.9446x; 2.0102x over previous
//
#include <hip/hip_runtime.h>

#define B_ 8
#define C_ 128
#define L_ 4096
#define P_ 96
#define D_ 16

typedef __attribute__((ext_vector_type(8))) short short8;
typedef __attribute__((ext_vector_type(16))) float float16v;

__device__ __forceinline__ unsigned short f2bf(float f) {
  unsigned int u = __float_as_uint(f);
  u += 0x7fff + ((u >> 16) & 1);          // round-to-nearest-even
  return (unsigned short)(u >> 16);
}

// ---------------------------------------------------------------------------
// Workspace layout (bytes)
// ---------------------------------------------------------------------------
constexpr size_t OFF_H      = 0;                      // h  [B][C][L] f32 : 16 MB
constexpr size_t OFF_PSUM   = 16777216;               // [C][2] f32
constexpr size_t OFF_PSUMSQ = OFF_PSUM + 8192;
constexpr size_t OFF_SCALE  = OFF_PSUMSQ + 8192;      // [C] f32
constexpr size_t OFF_SHIFT  = OFF_SCALE + 512;
constexpr size_t OFF_WALLT  = OFF_SHIFT + 512;        // WallT [c][r] f32 64 KB
constexpr size_t OFF_BALL   = OFF_WALLT + 65536;      // [128] f32
constexpr size_t OFF_QT     = OFF_BALL + 512;         // [B][L][16] bf16 (q pre-scaled by log2e)
constexpr size_t OFF_KT     = OFF_QT + 1048576;       // [B][L][16] bf16
constexpr size_t OFF_V2     = OFF_KT + 1048576;       // v2t [B][L/16][96][16] bf16 : 6 MB

// ---------------------------------------------------------------------------
// k_prep: rows 0..15 = Wq, 16..31 = Wk, 32..127 = Wv2 = W2 @ Wv.
// ---------------------------------------------------------------------------
__global__ __launch_bounds__(128) void k_prep(
    const float* __restrict__ Wq, const float* __restrict__ bq,
    const float* __restrict__ Wk, const float* __restrict__ bk,
    const float* __restrict__ Wv, const float* __restrict__ bv,
    const float* __restrict__ W2,
    float* __restrict__ wallT, float* __restrict__ ball)
{
  const int r = blockIdx.x;
  const int c = threadIdx.x;
  float wv;
  if (r < 16) {
    wv = Wq[r * C_ + c];
  } else if (r < 32) {
    wv = Wk[(r - 16) * C_ + c];
  } else {
    const int p = r - 32;
    float s = 0.f;
#pragma unroll 8
    for (int o = 0; o < C_; ++o) s += W2[p * C_ + o] * Wv[o * C_ + c];
    wv = s;
  }
  wallT[c * C_ + r] = wv;
  if (c == 0) {
    float bb;
    if (r < 16)      bb = bq[r];
    else if (r < 32) bb = bk[r - 16];
    else {
      const int p = r - 32;
      float s = 0.f;
#pragma unroll 8
      for (int o = 0; o < C_; ++o) s += W2[p * C_ + o] * bv[o];
      bb = s;
    }
    ball[r] = bb;
  }
}

// ---------------------------------------------------------------------------
// k_conv: h[b,o,l] = sum_i x[b,i] * Wt[i,o,l]. ~40 us/pass = at the 256 MB
// Wt read-once roofline (measured round 2). Unchanged.
// ---------------------------------------------------------------------------
__global__ __launch_bounds__(512) void k_conv(
    const float* __restrict__ x, const float* __restrict__ Wt,
    float* __restrict__ h, float* __restrict__ psum, float* __restrict__ psumsq)
{
  __shared__ float4 xs4[256];
  __shared__ float rs1[8], rs2[8];
  const int tid = threadIdx.x;
  const int o = blockIdx.y;
  const int l = blockIdx.x * 2048 + tid * 4;

  if (tid < 256) xs4[tid] = ((const float4*)x)[tid];
  __syncthreads();

  float4 acc[8];
#pragma unroll
  for (int bb = 0; bb < 8; ++bb) acc[bb] = (float4){0.f, 0.f, 0.f, 0.f};

  const float* wp = Wt + (size_t)o * L_ + l;
  const size_t stride = (size_t)C_ * L_;
  const int phase = (blockIdx.y + blockIdx.x * 8) & 31;

  float4 wbuf[2][4];
#pragma unroll
  for (int q = 0; q < 4; ++q)
    wbuf[0][q] = *(const float4*)(wp + (size_t)(phase * 4 + q) * stride);

#pragma unroll 2
  for (int g = 0; g < 32; ++g) {
    const int cur = g & 1, nb = cur ^ 1;
    const int in4 = ((phase + g + 1) & 31) * 4;
#pragma unroll
    for (int q = 0; q < 4; ++q)
      wbuf[nb][q] = *(const float4*)(wp + (size_t)(in4 + q) * stride);

    const int ic = (phase + g) & 31;
#pragma unroll
    for (int bb = 0; bb < 8; ++bb) {
      const float4 xb = xs4[bb * 32 + ic];
      acc[bb].x += xb.x * wbuf[cur][0].x + xb.y * wbuf[cur][1].x + xb.z * wbuf[cur][2].x + xb.w * wbuf[cur][3].x;
      acc[bb].y += xb.x * wbuf[cur][0].y + xb.y * wbuf[cur][1].y + xb.z * wbuf[cur][2].y + xb.w * wbuf[cur][3].y;
      acc[bb].z += xb.x * wbuf[cur][0].z + xb.y * wbuf[cur][1].z + xb.z * wbuf[cur][2].z + xb.w * wbuf[cur][3].z;
      acc[bb].w += xb.x * wbuf[cur][0].w + xb.y * wbuf[cur][1].w + xb.z * wbuf[cur][2].w + xb.w * wbuf[cur][3].w;
    }
  }
  float s1 = 0.f, s2 = 0.f;
#pragma unroll
  for (int bb = 0; bb < 8; ++bb) {
    *(float4*)(h + ((size_t)(bb * C_ + o)) * L_ + l) = acc[bb];
    s1 += acc[bb].x + acc[bb].y + acc[bb].z + acc[bb].w;
    s2 += acc[bb].x * acc[bb].x + acc[bb].y * acc[bb].y
        + acc[bb].z * acc[bb].z + acc[bb].w * acc[bb].w;
  }
  for (int off = 1; off < 64; off <<= 1) {
    s1 += __shfl_xor(s1, off);
    s2 += __shfl_xor(s2, off);
  }
  if ((tid & 63) == 0) { rs1[tid >> 6] = s1; rs2[tid >> 6] = s2; }
  __syncthreads();
  if (tid == 0) {
    float a1 = 0.f, a2 = 0.f;
#pragma unroll
    for (int wv = 0; wv < 8; ++wv) { a1 += rs1[wv]; a2 += rs2[wv]; }
    psum[o * 2 + blockIdx.x]   = a1;
    psumsq[o * 2 + blockIdx.x] = a2;
  }
}

// ---------------------------------------------------------------------------
// k_bn: finalize per-channel scale/shift.
// ---------------------------------------------------------------------------
__global__ __launch_bounds__(128) void k_bn(
    const float* __restrict__ psum, const float* __restrict__ psumsq,
    const float* __restrict__ gamma, const float* __restrict__ beta,
    float* __restrict__ scale, float* __restrict__ shift)
{
  const int c = threadIdx.x;
  float s1 = 0.f, s2 = 0.f;
  for (int t = 0; t < 2; ++t) { s1 += psum[c * 2 + t]; s2 += psumsq[c * 2 + t]; }
  const float inv = 1.f / 32768.f;
  const float mean = s1 * inv;
  const float var  = s2 * inv - mean * mean;
  const float sc   = rsqrtf(var + 1e-5f) * gamma[c];
  scale[c] = sc;
  shift[c] = beta[c] - mean * sc;
}

// ---------------------------------------------------------------------------
// k_proj: [q;k;v2] = Wall @ relu(bn(h)) + ball, bf16 out. ~16 us (measured).
// XCD-pinned: blockIdx.x = batch -> linear bid = b + 8*ltile -> xcd = b, so
// qT/kT/v2t WRITES land in the same XCD's L2 that k_attn will read them from.
// ---------------------------------------------------------------------------
__global__ __launch_bounds__(256) void k_proj(
    const float* __restrict__ h, const float* __restrict__ scale,
    const float* __restrict__ shift, const float* __restrict__ wallT,
    const float* __restrict__ ball,
    unsigned short* __restrict__ qT, unsigned short* __restrict__ kT,
    unsigned short* __restrict__ v2t)
{
  __shared__ __align__(16) char sm[128 * 68 * 4];     // 34 KB
  float* hn = (float*)sm;                             // [c][68] f32, 64 used
  unsigned short* v2s = (unsigned short*)sm;          // reused: [p][72] bf16

  const int b  = blockIdx.x;          // batch -> XCD selector
  const int lx = blockIdx.y;          // l-tile 0..63
  const int l0 = lx * 64;
  const int tid = threadIdx.x;

#pragma unroll
  for (int i = 0; i < 8; ++i) {
    const int idx = tid + i * 256;
    const int c = idx >> 4, lq = (idx & 15) * 4;
    const float4 hv = *(const float4*)(h + ((size_t)(b * C_ + c)) * L_ + l0 + lq);
    const float sc = scale[c], sh = shift[c];
    float4 r;
    r.x = fmaxf(hv.x * sc + sh, 0.f);
    r.y = fmaxf(hv.y * sc + sh, 0.f);
    r.z = fmaxf(hv.z * sc + sh, 0.f);
    r.w = fmaxf(hv.w * sc + sh, 0.f);
    *(float4*)(hn + c * 68 + lq) = r;
  }
  __syncthreads();

  const int wu = __builtin_amdgcn_readfirstlane(tid) >> 6;  // wave id, uniform
  const int lane = tid & 63;
  const int l = l0 + lane;

  float acc[32];
#pragma unroll
  for (int r = 0; r < 32; ++r) acc[r] = ball[wu * 32 + r];

#pragma unroll 4
  for (int c = 0; c < C_; ++c) {
    const float hv = hn[c * 68 + lane];
    const float* wrow = wallT + c * C_ + wu * 32;   // wave-uniform: s_load
#pragma unroll
    for (int r = 0; r < 32; ++r) acc[r] += wrow[r] * hv;
  }
  __syncthreads();   // all waves done reading hn before LDS reuse

  if (wu == 0) {
    const size_t row = (size_t)(b * L_ + l) * D_;
    short8 v0, v1;
#pragma unroll
    for (int r = 0; r < 8; ++r) {
      v0[r] = (short)f2bf(acc[r] * 1.44269504f);        // q * log2(e)
      v1[r] = (short)f2bf(acc[8 + r] * 1.44269504f);
    }
    *(short8*)(qT + row) = v0;  *(short8*)(qT + row + 8) = v1;
#pragma unroll
    for (int r = 0; r < 8; ++r) { v0[r] = (short)f2bf(acc[16 + r]); v1[r] = (short)f2bf(acc[24 + r]); }
    *(short8*)(kT + row) = v0;  *(short8*)(kT + row + 8) = v1;
  } else {
    const int pbase = wu * 32 - 32;
#pragma unroll
    for (int r = 0; r < 32; ++r)
      v2s[(pbase + r) * 72 + lane] = f2bf(acc[r]);
  }
  __syncthreads();

  // v2 stores, m-tiled: fully coalesced consecutive 8B stores
#pragma unroll
  for (int i = 0; i < 6; ++i) {
    const int j = tid + i * 256;
    const int mo4 = j & 3;
    const int jp = j >> 2;
    const int p = jp % 96;
    const int mtl = jp / 96;                       // 0..3
    const uint2 val = *(const uint2*)(v2s + p * 72 + mtl * 16 + mo4 * 4);
    *(uint2*)(v2t + ((size_t)((b * (L_ / 16) + lx * 4 + mtl)) * P_ + p) * 16
              + mo4 * 4) = val;
  }
}

// ---------------------------------------------------------------------------
// k_attn v4 = round-2 structure (verified 106 us/pass; VGPR 64 + AGPR 64 =
// exactly 4 waves/SIMD -- the register-floor occupancy ceiling; round-3's
// 8-wave target spilled 1.8 GB to scratch and is abandoned) + XCD batch
// pinning. Round-2 PMC: FETCH 36 MB/rep vs 8 MB working set -> L2 thrash
// because round-robin dispatch makes every XCD's 4 MB L2 hold all 8 batches'
// K/V (8 MB). Now blockIdx.x = batch -> linear bid = b + 8*ltile -> xcd = b:
// each XCD serves ONE batch (kT 256 KB + v2t 768 KB = 1 MB < 4 MB), so the
// per-iteration V/K fragment loads become L2 hits instead of LLC round trips.
// ---------------------------------------------------------------------------
__global__ __launch_bounds__(1024, 4) void k_attn(
    const unsigned short* __restrict__ qT, const unsigned short* __restrict__ kT,
    const unsigned short* __restrict__ v2t, const float* __restrict__ b2,
    float* __restrict__ y)
{
  __shared__ float ldsO[P_ * 128];   // [p][l] 48 KB
  __shared__ float ldsL[128];

  const int b  = blockIdx.x;          // batch -> XCD selector
  const int l0 = blockIdx.y * 128;    // l-tile
  const int tid = threadIdx.x;
  const int w  = tid >> 6;
  const int qg = w & 3;          // q-group
  const int ms = w >> 2;         // m-slice
  const int lane = tid & 63;
  const int col = lane & 31;
  const int hh  = lane >> 5;     // half-wave

#pragma unroll
  for (int i = 0; i < 12; ++i) ldsO[tid + i * 1024] = 0.f;
  if (tid < 128) ldsL[tid] = 0.f;
  __syncthreads();

  // Q^T B-fragment: B[k=8*hh+j][n=col], row lq of qT
  const int lq = l0 + qg * 32 + col;
  const short8 qf = *(const short8*)(qT + ((size_t)(b * L_ + lq)) * D_ + hh * 8);

  float16v oacc[3];
#pragma unroll
  for (int pt = 0; pt < 3; ++pt)
#pragma unroll
    for (int r = 0; r < 16; ++r) oacc[pt][r] = 0.f;
  float lsum = 0.f;

  const unsigned short* kbase =
      kT + ((size_t)(b * L_ + ms * 1024 + col)) * D_ + hh * 8;
  // v2t base for this batch; fragment (mt16, pt) at ((mt16)*96 + pt*32+col)*16 + hh*8
  const unsigned short* vtb = v2t + (size_t)b * (L_ / 16) * P_ * 16
                              + (size_t)col * 16 + hh * 8;

  short8 kf_cur = *(const short8*)(kbase);

#pragma unroll 2
  for (int it = 0; it < 32; ++it) {
    // prefetch next K-frag (head of the S dependency chain)
    const int itn = (it + 1) & 31;                 // wrap: always valid
    const short8 kf_nxt = *(const short8*)(kbase + (size_t)itn * 32 * D_);

    float16v zero;
#pragma unroll
    for (int r = 0; r < 16; ++r) zero[r] = 0.f;
    const float16v s = __builtin_amdgcn_mfma_f32_32x32x16_bf16(kf_cur, qf, zero, 0, 0, 0);

    const int mt16 = ms * 64 + it * 2;             // m-tile index (16 m per tile)

#pragma unroll
    for (int mt = 0; mt < 2; ++mt) {
      // issue this 16-m chunk's V-frags first; the exp chain hides their latency
      short8 vf[3];
#pragma unroll
      for (int pt = 0; pt < 3; ++pt)
        vf[pt] = *(const short8*)(vtb + ((size_t)(mt16 + mt) * P_ + pt * 32) * 16);

      // P = exp2(S^T) for this chunk; pack bf16 pairs
      unsigned dw[4];
#pragma unroll
      for (int g = 0; g < 4; ++g) {
        const float e0 = __builtin_amdgcn_exp2f(s[8 * mt + 2 * g]);
        const float e1 = __builtin_amdgcn_exp2f(s[8 * mt + 2 * g + 1]);
        lsum += e0 + e1;
        const unsigned u0 = __float_as_uint(e0) + 0x8000u;
        const unsigned u1 = __float_as_uint(e1) + 0x8000u;
        dw[g] = __builtin_amdgcn_perm(u1, u0, 0x07060302u);  // (bf(e1)<<16)|bf(e0)
      }

      // build P^T B-frag for k = mt*16 + 8*hh + j via half-wave exchange
      const unsigned t0 = hh ? dw[0] : dw[2];
      const unsigned t1 = hh ? dw[1] : dw[3];
      const unsigned r0 = (unsigned)__shfl_xor((int)t0, 32);
      const unsigned r1 = (unsigned)__shfl_xor((int)t1, 32);
      union { int4 i; short8 s8; } pu;
      pu.i.x = hh ? (int)r0 : (int)dw[0];
      pu.i.y = hh ? (int)r1 : (int)dw[1];
      pu.i.z = hh ? (int)dw[2] : (int)r0;
      pu.i.w = hh ? (int)dw[3] : (int)r1;
      const short8 pf = pu.s8;
#pragma unroll
      for (int pt = 0; pt < 3; ++pt)
        oacc[pt] = __builtin_amdgcn_mfma_f32_32x32x16_bf16(vf[pt], pf, oacc[pt], 0, 0, 0);
    }
    kf_cur = kf_nxt;
  }

  // combine partials across m-slices (and half-waves) in LDS
  atomicAdd(&ldsL[qg * 32 + col], lsum);
#pragma unroll
  for (int pt = 0; pt < 3; ++pt)
#pragma unroll
    for (int r = 0; r < 16; ++r) {
      const int p = (r & 3) + 8 * (r >> 2) + 4 * hh + 32 * pt;
      atomicAdd(&ldsO[p * 128 + qg * 32 + col], oacc[pt][r]);
    }
  __syncthreads();

  // y[b,p,l0+l] = O^T[p][l]/lsum[l] + b2[p]
#pragma unroll
  for (int i = 0; i < 12; ++i) {
    const int idx = tid + i * 1024;
    const int p = idx >> 7;
    const int l = idx & 127;
    y[((size_t)(b * P_ + p)) * L_ + l0 + l] = ldsO[idx] / ldsL[l] + b2[p];
  }
}

// ---------------------------------------------------------------------------
extern "C" void kernel_launch(void* const* d_in, const int* in_sizes, int n_in,
                              void* d_out, int out_size, void* d_ws, size_t ws_size,
                              hipStream_t stream) {
  (void)in_sizes; (void)n_in; (void)out_size; (void)ws_size;
  const float* x     = (const float*)d_in[0];
  const float* Wt    = (const float*)d_in[1];
  // d_in[2] = bt: unused — BatchNorm mean-subtraction cancels it exactly.
  const float* gamma = (const float*)d_in[3];
  const float* beta  = (const float*)d_in[4];
  const float* Wq    = (const float*)d_in[5];
  const float* bq    = (const float*)d_in[6];
  const float* Wk    = (const float*)d_in[7];
  const float* bk    = (const float*)d_in[8];
  const float* Wv    = (const float*)d_in[9];
  const float* bv    = (const float*)d_in[10];
  const float* W2    = (const float*)d_in[11];
  const float* b2    = (const float*)d_in[12];
  float* y = (float*)d_out;

  char* ws = (char*)d_ws;
  float* h       = (float*)(ws + OFF_H);
  float* psum    = (float*)(ws + OFF_PSUM);
  float* psumsq  = (float*)(ws + OFF_PSUMSQ);
  float* scale   = (float*)(ws + OFF_SCALE);
  float* shift   = (float*)(ws + OFF_SHIFT);
  float* wallT   = (float*)(ws + OFF_WALLT);
  float* ball    = (float*)(ws + OFF_BALL);
  unsigned short* qT  = (unsigned short*)(ws + OFF_QT);
  unsigned short* kT  = (unsigned short*)(ws + OFF_KT);
  unsigned short* v2t = (unsigned short*)(ws + OFF_V2);

  k_prep<<<128, 128, 0, stream>>>(Wq, bq, Wk, bk, Wv, bv, W2, wallT, ball);
  k_conv<<<dim3(2, 128), 512, 0, stream>>>(x, Wt, h, psum, psumsq);
  k_bn<<<1, 128, 0, stream>>>(psum, psumsq, gamma, beta, scale, shift);
  // batch -> XCD pinning: blockIdx.x = batch, so linear bid % 8 = batch.
  k_proj<<<dim3(8, 64), 256, 0, stream>>>(h, scale, shift, wallT, ball, qT, kT, v2t);
  k_attn<<<dim3(8, 32), 1024, 0, stream>>>(qT, kT, v2t, b2, y);
}